// Round 19
// baseline (226.737 us; speedup 1.0000x reference)
//
#include <hip/hip_runtime.h>
#include <cstddef>
#include <cstdint>

#define NPTS 10000
#define TDIM 64
#define CINDIM 64
#define FDIM 64
#define HIDDIM 128
#define SDIM 8
#define NG 2     // n's per block in matmul kernels (r19: 4->2, 5000 blocks
                 // kills the ~40% block-quantization tail at 2500 blocks)
#define GNB 2000 // gather blocks (250 per XCD; all co-resident)

typedef _Float16 f16;
typedef _Float16 f16x2 __attribute__((ext_vector_type(2)));
typedef _Float16 f16x4 __attribute__((ext_vector_type(4)));
typedef _Float16 f16x8 __attribute__((ext_vector_type(8)));
typedef float f32x4 __attribute__((ext_vector_type(4)));
typedef float f32x16 __attribute__((ext_vector_type(16)));

#define MFMA32(a, b, c) __builtin_amdgcn_mfma_f32_32x32x16_f16((a), (b), (c), 0, 0, 0)

static __device__ __forceinline__ f16x2 pk(float a, float b) {
  return __builtin_bit_cast(f16x2, __builtin_amdgcn_cvt_pkrtz(a, b));
}
static __device__ __forceinline__ f16x4 pack4(f32x4 p) {
  f16x2 h0 = pk(p[0], p[1]), h1 = pk(p[2], p[3]);
  return __builtin_shufflevector(h0, h1, 0, 1, 2, 3);
}
static __device__ __forceinline__ f16x4 pack4_relu(f32x4 v, f32x4 bias) {
  f16x4 r;
  r[0] = (f16)fmaxf(v[0] + bias[0], 0.f);
  r[1] = (f16)fmaxf(v[1] + bias[1], 0.f);
  r[2] = (f16)fmaxf(v[2] + bias[2], 0.f);
  r[3] = (f16)fmaxf(v[3] + bias[3], 0.f);
  return r;
}

// ---------------------------------------------------------------------------
// prep: round weights to f16 and pre-shuffle into 32x32x16 A-frag order:
// lane l holds A[row=l&31][kk=(l>>5)*8+j]. Storage [slice][ks][lane][j],
// kk = ks*16+(l>>5)*8+j.
//   conv1 kk = k*64 + c   (K=192, 12 ks, 2 slices)
//   fc    kk = c          (K=128,  8 ks, 4 slices)
//   conv2 kk = k*128 + c  (K=384, 24 ks, 2 slices)
// ---------------------------------------------------------------------------
__global__ __launch_bounds__(256) void prep_kernel(
    const float* __restrict__ W1, const float* __restrict__ Wfc,
    const float* __restrict__ W2, f16* __restrict__ w1h,
    f16* __restrict__ wfh, f16* __restrict__ w2h) {
  const int idx = blockIdx.x * 256 + threadIdx.x;
  const int j = idx & 7;
  if (idx < 2 * 12 * 512) {  // w1
    const int s = idx / 6144, rem = idx % 6144;
    const int ks = rem / 512, l = (rem % 512) >> 3;
    const int kk = ks * 16 + ((l >> 5) << 3) + j;
    const int k = kk >> 6, c = kk & 63, f = s * 32 + (l & 31);
    w1h[idx] = (f16)W1[f * 192 + c * 3 + k];
  }
  if (idx < 4 * 8 * 512) {  // wfc
    const int s = idx / 4096, rem = idx % 4096;
    const int ks = rem / 512, l = (rem % 512) >> 3;
    const int kk = ks * 16 + ((l >> 5) << 3) + j;
    const int hc = s * 32 + (l & 31);
    wfh[idx] = (f16)Wfc[hc * 128 + kk];
  }
  if (idx < 2 * 24 * 512) {  // w2
    const int s = idx / 12288, rem = idx % 12288;
    const int ks = rem / 512, l = (rem % 512) >> 3;
    const int kk = ks * 16 + ((l >> 5) << 3) + j;
    const int k = kk >> 7, c = kk & 127, f = s * 32 + (l & 31);
    w2h[idx] = (f16)W2[f * 384 + c * 3 + k];
  }
}

// ---------------------------------------------------------------------------
// conv1: relu(b1 + sum_{k,c} W1[f,c,k] x[n, t-4+2k, c]). LDS-staged: x[n]
// tile (64x64 fp32) loaded coalesced, packed to f16 into xs[68][72] (rows
// 0-3 = causal zero pad). Wave w: M-slice s=w>>1, t-half th=w&1. h16t only.
// ---------------------------------------------------------------------------
__global__ __launch_bounds__(256) void conv1_kernel(
    const float* __restrict__ x, const f16* __restrict__ w1h,
    const float* __restrict__ b1, f16* __restrict__ h16t) {
  __shared__ f16 xs[68 * 72];
  const int tid = threadIdx.x;
  const int w = tid >> 6, lane = tid & 63;
  const int s = w >> 1, th = w & 1;
  const int rl = lane & 31, hi = lane >> 5;
  f16x8 wh[12];
#pragma unroll
  for (int ks = 0; ks < 12; ++ks)
    wh[ks] = *(const f16x8*)&w1h[((s * 12 + ks) * 64 + lane) * 8];
  f32x4 bias[4];
#pragma unroll
  for (int q = 0; q < 4; ++q) bias[q] = *(const f32x4*)&b1[s * 32 + 8 * q + 4 * hi];
  // rows 0-3 (causal pad) = 288 f16 = 144 f16x2; 144 <= 256 threads -> full.
  if (tid < 144) ((f16x2*)xs)[tid] = (f16x2){(f16)0, (f16)0};

  for (int g = 0; g < NG; ++g) {
    const int n = blockIdx.x * NG + g;
    const float* xn = x + (size_t)n * (TDIM * CINDIM);
    if (g) __syncthreads();  // previous compute done before overwrite
#pragma unroll
    for (int pass = 0; pass < 4; ++pass) {  // 64 rows x 16 chunks of 4 fp32
      const int idx = pass * 256 + tid;
      const int row = idx >> 4, c4 = (idx & 15) * 4;
      const f32x4 v = *(const f32x4*)&xn[row * 64 + c4];
      *(f16x4*)&xs[(row + 4) * 72 + c4] = pack4(v);
    }
    __syncthreads();

    f32x16 acc;
#pragma unroll
    for (int i = 0; i < 16; ++i) acc[i] = 0.f;
#pragma unroll
    for (int ks = 0; ks < 12; ++ks) {
      const int k = ks >> 2;
      const int c0 = (ks & 3) * 16 + hi * 8;
      const f16x8 b = *(const f16x8*)&xs[(th * 32 + rl + 2 * k) * 72 + c0];
      acc = MFMA32(wh[ks], b, acc);
    }
    const int t = th * 32 + rl;
    f16* hrowt = h16t + ((size_t)t * NPTS + n) * 64;
#pragma unroll
    for (int q = 0; q < 4; ++q) {
      const f32x4 sub = {acc[4 * q], acc[4 * q + 1], acc[4 * q + 2], acc[4 * q + 3]};
      *(f16x4*)&hrowt[s * 32 + 8 * q + 4 * hi] = pack4_relu(sub, bias[q]);
    }
  }
}

// ---------------------------------------------------------------------------
// gather: agg16t[t][n][:] = masked-mean_s h16t[t][idx[t,n,s]][:] (fallback
// self). Octet per (t,n) pair; lane reads 16B -> one wave gather serves 8
// pairs; idx/mask = one coalesced wave load each, broadcast via __shfl.
// agg is T-MAJOR: one store instr writes 8 consecutive n rows = 1KB
// contiguous. Plain loads/stores only (r17: nontemporal broke integrity).
// Walk: 250 blocks/XCD, stride 8000, 10 iters, <=2 concurrent t-slabs/XCD.
// ---------------------------------------------------------------------------
__global__ __launch_bounds__(256) void gather_kernel(
    const f16* __restrict__ h16t, const int* __restrict__ nidx,
    const int* __restrict__ nmask, f16* __restrict__ agg16t) {
  const int tid = threadIdx.x;
  const int wv = tid >> 6, lane = tid & 63;
  const int oct = lane >> 3, sl8 = lane & 7;            // octet, sublane
  const int xcd = blockIdx.x & 7, q = blockIdx.x >> 3;  // q in [0,250)
  const uint4* h128 = (const uint4*)h16t;               // 16B units
  uint4* agg128 = (uint4*)agg16t;

  int t = xcd * 8;
  int n = (q * 4 + wv) * 8;  // octet base in [0,8000), 8-aligned
  int ci, cm;
  {
    const size_t pr = ((size_t)t * NPTS + n) * SDIM;
    ci = nidx[pr + lane];
    cm = nmask[pr + lane];
  }
  for (int j = 0; j < 10; ++j) {
    int tn = t, nn = n + 8000;
    if (nn >= NPTS) { nn -= NPTS; ++tn; }  // stride < NPTS: at most one wrap
    int pi = 0, pm = 0;
    if (j + 1 < 10) {  // prefetch next octet-group's idx/mask
      const size_t pr = ((size_t)tn * NPTS + nn) * SDIM;
      pi = nidx[pr + lane];
      pm = nmask[pr + lane];
    }
    const uint32_t tb = (uint32_t)t * (NPTS * 8) + sl8;  // uint4 units
    uint4 u[8];
#pragma unroll
    for (int s = 0; s < SDIM; ++s) {
      const int is = __shfl(ci, oct * 8 + s, 64);
      u[s] = h128[tb + (uint32_t)is * 8u];
    }
    float a[8] = {0.f, 0.f, 0.f, 0.f, 0.f, 0.f, 0.f, 0.f};
    float cnt = 0.f;
#pragma unroll
    for (int s = 0; s < SDIM; ++s) {
      const float m = (__shfl(cm, oct * 8 + s, 64) != 0) ? 1.f : 0.f;
      const f16x2 p0 = __builtin_bit_cast(f16x2, u[s].x);
      const f16x2 p1 = __builtin_bit_cast(f16x2, u[s].y);
      const f16x2 p2 = __builtin_bit_cast(f16x2, u[s].z);
      const f16x2 p3 = __builtin_bit_cast(f16x2, u[s].w);
      a[0] = fmaf(m, (float)p0[0], a[0]);
      a[1] = fmaf(m, (float)p0[1], a[1]);
      a[2] = fmaf(m, (float)p1[0], a[2]);
      a[3] = fmaf(m, (float)p1[1], a[3]);
      a[4] = fmaf(m, (float)p2[0], a[4]);
      a[5] = fmaf(m, (float)p2[1], a[5]);
      a[6] = fmaf(m, (float)p3[0], a[6]);
      a[7] = fmaf(m, (float)p3[1], a[7]);
      cnt += m;
    }
    uint4 outv;
    if (cnt > 0.f) {
      const float inv = 1.f / cnt;
      const f16x4 lo4 = pack4((f32x4){a[0] * inv, a[1] * inv, a[2] * inv, a[3] * inv});
      const f16x4 hi4 = pack4((f32x4){a[4] * inv, a[5] * inv, a[6] * inv, a[7] * inv});
      const uint2 lo = __builtin_bit_cast(uint2, lo4);
      const uint2 hi = __builtin_bit_cast(uint2, hi4);
      outv.x = lo.x; outv.y = lo.y; outv.z = hi.x; outv.w = hi.y;
    } else {  // fallback: self row (exec-masked)
      outv = h128[tb + (uint32_t)(n + oct) * 8u];
    }
    // t-major: octets 0..7 -> consecutive n rows -> 1KB contiguous/instr
    agg128[((size_t)t * NPTS + (n + oct)) * 8 + sl8] = outv;
    ci = pi; cm = pm; t = tn; n = nn;
  }
}

// ---------------------------------------------------------------------------
// fused fc+conv2: z never touches global (saves its 328MB round-trip).
// Per g: stage hs/as (BOTH t-major: row (t,n) = one full 128B line) ->
// fc MFMA (wave w owns hc slice [32w,32w+32), both t-halves) writes relu(z)
// f16 into zs[68][136] LDS (rows 0-3 = causal pad) -> barrier -> conv2 MFMA
// (wave w: M-slice w>>1, t-half w&1) -> out fp32.
// ---------------------------------------------------------------------------
__global__ __launch_bounds__(256) void fc_conv2_kernel(
    const f16* __restrict__ h16t, const f16* __restrict__ agg16t,
    const f16* __restrict__ wfh, const float* __restrict__ bfc,
    const f16* __restrict__ w2h, const float* __restrict__ b2,
    float* __restrict__ out) {
  __shared__ f16 hs[64 * 72];
  __shared__ f16 as2[64 * 72];
  __shared__ f16 zs[68 * 136];
  const int tid = threadIdx.x;
  const int w = tid >> 6, lane = tid & 63;
  const int rl = lane & 31, hi = lane >> 5;
  f16x8 whf[8];
#pragma unroll
  for (int ks = 0; ks < 8; ++ks)
    whf[ks] = *(const f16x8*)&wfh[((w * 8 + ks) * 64 + lane) * 8];
  f32x4 biasf[4];
#pragma unroll
  for (int q = 0; q < 4; ++q)
    biasf[q] = *(const f32x4*)&bfc[w * 32 + 8 * q + 4 * hi];
  const int s2 = w >> 1, th2 = w & 1;
  f16x8 wh2[24];
#pragma unroll
  for (int ks = 0; ks < 24; ++ks)
    wh2[ks] = *(const f16x8*)&w2h[((s2 * 24 + ks) * 64 + lane) * 8];
  f32x4 bias2[4];
#pragma unroll
  for (int q = 0; q < 4; ++q)
    bias2[q] = *(const f32x4*)&b2[s2 * 32 + 8 * q + 4 * hi];
  // zs rows 0-3 (causal pad) = 544 f16 = 136 f16x4, within 256 threads.
  if (tid < 136) ((f16x4*)zs)[tid] = (f16x4){(f16)0, (f16)0, (f16)0, (f16)0};

  for (int g = 0; g < NG; ++g) {
    const int n = blockIdx.x * NG + g;
    if (g) __syncthreads();  // prev conv2 done with zs, prev fc done with hs/as
#pragma unroll
    for (int pass = 0; pass < 2; ++pass) {  // 64 rows x 8 chunks of 8 f16
      const int idx = pass * 256 + tid;
      const int row = idx >> 3, c8 = (idx & 7) * 8;
      *(f16x8*)&hs[row * 72 + c8] =
          *(const f16x8*)&h16t[((size_t)row * NPTS + n) * 64 + c8];
      *(f16x8*)&as2[row * 72 + c8] =
          *(const f16x8*)&agg16t[((size_t)row * NPTS + n) * 64 + c8];
    }
    __syncthreads();

    // fc phase: z[t][32w..32w+32) for all 64 t
#pragma unroll
    for (int tf = 0; tf < 2; ++tf) {
      f32x16 accf;
#pragma unroll
      for (int i = 0; i < 16; ++i) accf[i] = 0.f;
      const int t = tf * 32 + rl;
#pragma unroll
      for (int ks = 0; ks < 8; ++ks) {
        const int c0 = (ks & 3) * 16 + hi * 8;
        const f16x8 b = (ks < 4) ? *(const f16x8*)&hs[t * 72 + c0]
                                 : *(const f16x8*)&as2[t * 72 + c0];
        accf = MFMA32(whf[ks], b, accf);
      }
#pragma unroll
      for (int q = 0; q < 4; ++q) {
        const f32x4 sub = {accf[4 * q], accf[4 * q + 1], accf[4 * q + 2], accf[4 * q + 3]};
        *(f16x4*)&zs[(t + 4) * 136 + w * 32 + 8 * q + 4 * hi] =
            pack4_relu(sub, biasf[q]);
      }
    }
    __syncthreads();

    // conv2 phase
    f32x16 acc;
#pragma unroll
    for (int i = 0; i < 16; ++i) acc[i] = 0.f;
#pragma unroll
    for (int ks = 0; ks < 24; ++ks) {
      const int k = ks >> 3;
      const int c0 = (ks & 7) * 16 + hi * 8;
      const f16x8 b = *(const f16x8*)&zs[(th2 * 32 + rl + 2 * k) * 136 + c0];
      acc = MFMA32(wh2[ks], b, acc);
    }
    const int t = th2 * 32 + rl;
    float* orow = out + ((size_t)n * 64 + t) * 64;
#pragma unroll
    for (int q = 0; q < 4; ++q) {
      f32x4 v;
      v[0] = fmaxf(acc[4 * q + 0] + bias2[q][0], 0.f);
      v[1] = fmaxf(acc[4 * q + 1] + bias2[q][1], 0.f);
      v[2] = fmaxf(acc[4 * q + 2] + bias2[q][2], 0.f);
      v[3] = fmaxf(acc[4 * q + 3] + bias2[q][3], 0.f);
      *(f32x4*)&orow[s2 * 32 + 8 * q + 4 * hi] = v;
    }
  }
}

// ---------------------------------------------------------------------------
// Workspace (f16 units): w1h 12288 | wfh 16384 | w2h 24576 |
//   h16t 41M (t-major) | agg16t 41M (t-major)   ~164 MB.
// ---------------------------------------------------------------------------
extern "C" void kernel_launch(void* const* d_in, const int* in_sizes, int n_in,
                              void* d_out, int out_size, void* d_ws, size_t ws_size,
                              hipStream_t stream) {
  (void)in_sizes; (void)n_in; (void)out_size; (void)ws_size;
  const float* x   = (const float*)d_in[0];
  const float* W1  = (const float*)d_in[1];
  const float* b1  = (const float*)d_in[2];
  const float* Wfc = (const float*)d_in[3];
  const float* bfc = (const float*)d_in[4];
  const float* W2  = (const float*)d_in[5];
  const float* b2  = (const float*)d_in[6];
  const int* nidx  = (const int*)d_in[7];
  const int* nmask = (const int*)d_in[8];
  float* out = (float*)d_out;

  f16* wsf = (f16*)d_ws;
  f16* w1h = wsf;
  f16* wfh = w1h + 12288;
  f16* w2h = wfh + 16384;
  f16* h16t = w2h + 24576;
  f16* agg16t = h16t + (size_t)NPTS * TDIM * FDIM;

  prep_kernel<<<96, 256, 0, stream>>>(W1, Wfc, W2, w1h, wfh, w2h);
  conv1_kernel<<<NPTS / NG, 256, 0, stream>>>(x, w1h, b1, h16t);
  gather_kernel<<<GNB, 256, 0, stream>>>(h16t, nidx, nmask, agg16t);
  fc_conv2_kernel<<<NPTS / NG, 256, 0, stream>>>(h16t, agg16t, wfh, bfc,
                                                 w2h, b2, out);
}

// Round 20
// 217.075 us; speedup vs baseline: 1.0445x; 1.0445x over previous
//
#include <hip/hip_runtime.h>
#include <cstddef>
#include <cstdint>

#define NPTS 10000
#define TDIM 64
#define CINDIM 64
#define FDIM 64
#define HIDDIM 128
#define SDIM 8
#define NG 4      // n's per block in fc_conv2 (r19 lesson: heavy preamble ->
                  // NG=2 regressed it 80->94us; keep 4)
#define CNG 2     // n's per block in conv1 (light preamble, VGPR<64 ->
                  // finer grid halves the quantization tail)
#define GNB 1000  // gather blocks (125/XCD; ~16 waves/CU = the VGPR cap at
                  // the 2-deep pipeline's ~100 VGPR)
#define GJ 20     // gather iterations per block
#define GSTRIDE 4000

typedef _Float16 f16;
typedef _Float16 f16x2 __attribute__((ext_vector_type(2)));
typedef _Float16 f16x4 __attribute__((ext_vector_type(4)));
typedef _Float16 f16x8 __attribute__((ext_vector_type(8)));
typedef float f32x4 __attribute__((ext_vector_type(4)));
typedef float f32x16 __attribute__((ext_vector_type(16)));

#define MFMA32(a, b, c) __builtin_amdgcn_mfma_f32_32x32x16_f16((a), (b), (c), 0, 0, 0)

static __device__ __forceinline__ f16x2 pk(float a, float b) {
  return __builtin_bit_cast(f16x2, __builtin_amdgcn_cvt_pkrtz(a, b));
}
static __device__ __forceinline__ f16x4 pack4(f32x4 p) {
  f16x2 h0 = pk(p[0], p[1]), h1 = pk(p[2], p[3]);
  return __builtin_shufflevector(h0, h1, 0, 1, 2, 3);
}
static __device__ __forceinline__ f16x4 pack4_relu(f32x4 v, f32x4 bias) {
  f16x4 r;
  r[0] = (f16)fmaxf(v[0] + bias[0], 0.f);
  r[1] = (f16)fmaxf(v[1] + bias[1], 0.f);
  r[2] = (f16)fmaxf(v[2] + bias[2], 0.f);
  r[3] = (f16)fmaxf(v[3] + bias[3], 0.f);
  return r;
}

// ---------------------------------------------------------------------------
// prep: round weights to f16 and pre-shuffle into 32x32x16 A-frag order:
// lane l holds A[row=l&31][kk=(l>>5)*8+j]. Storage [slice][ks][lane][j],
// kk = ks*16+(l>>5)*8+j.
//   conv1 kk = k*64 + c   (K=192, 12 ks, 2 slices)
//   fc    kk = c          (K=128,  8 ks, 4 slices)
//   conv2 kk = k*128 + c  (K=384, 24 ks, 2 slices)
// ---------------------------------------------------------------------------
__global__ __launch_bounds__(256) void prep_kernel(
    const float* __restrict__ W1, const float* __restrict__ Wfc,
    const float* __restrict__ W2, f16* __restrict__ w1h,
    f16* __restrict__ wfh, f16* __restrict__ w2h) {
  const int idx = blockIdx.x * 256 + threadIdx.x;
  const int j = idx & 7;
  if (idx < 2 * 12 * 512) {  // w1
    const int s = idx / 6144, rem = idx % 6144;
    const int ks = rem / 512, l = (rem % 512) >> 3;
    const int kk = ks * 16 + ((l >> 5) << 3) + j;
    const int k = kk >> 6, c = kk & 63, f = s * 32 + (l & 31);
    w1h[idx] = (f16)W1[f * 192 + c * 3 + k];
  }
  if (idx < 4 * 8 * 512) {  // wfc
    const int s = idx / 4096, rem = idx % 4096;
    const int ks = rem / 512, l = (rem % 512) >> 3;
    const int kk = ks * 16 + ((l >> 5) << 3) + j;
    const int hc = s * 32 + (l & 31);
    wfh[idx] = (f16)Wfc[hc * 128 + kk];
  }
  if (idx < 2 * 24 * 512) {  // w2
    const int s = idx / 12288, rem = idx % 12288;
    const int ks = rem / 512, l = (rem % 512) >> 3;
    const int kk = ks * 16 + ((l >> 5) << 3) + j;
    const int k = kk >> 7, c = kk & 127, f = s * 32 + (l & 31);
    w2h[idx] = (f16)W2[f * 384 + c * 3 + k];
  }
}

// ---------------------------------------------------------------------------
// conv1: relu(b1 + sum_{k,c} W1[f,c,k] x[n, t-4+2k, c]). LDS-staged: x[n]
// tile (64x64 fp32) loaded coalesced, packed to f16 into xs[68][72] (rows
// 0-3 = causal zero pad). Wave w: M-slice s=w>>1, t-half th=w&1. h16t only.
// CNG=2 (r20): grid 5000 halves the block-quantization tail; preamble light.
// ---------------------------------------------------------------------------
__global__ __launch_bounds__(256) void conv1_kernel(
    const float* __restrict__ x, const f16* __restrict__ w1h,
    const float* __restrict__ b1, f16* __restrict__ h16t) {
  __shared__ f16 xs[68 * 72];
  const int tid = threadIdx.x;
  const int w = tid >> 6, lane = tid & 63;
  const int s = w >> 1, th = w & 1;
  const int rl = lane & 31, hi = lane >> 5;
  f16x8 wh[12];
#pragma unroll
  for (int ks = 0; ks < 12; ++ks)
    wh[ks] = *(const f16x8*)&w1h[((s * 12 + ks) * 64 + lane) * 8];
  f32x4 bias[4];
#pragma unroll
  for (int q = 0; q < 4; ++q) bias[q] = *(const f32x4*)&b1[s * 32 + 8 * q + 4 * hi];
  // rows 0-3 (causal pad) = 288 f16 = 144 f16x2; 144 <= 256 threads -> full.
  if (tid < 144) ((f16x2*)xs)[tid] = (f16x2){(f16)0, (f16)0};

  for (int g = 0; g < CNG; ++g) {
    const int n = blockIdx.x * CNG + g;
    const float* xn = x + (size_t)n * (TDIM * CINDIM);
    if (g) __syncthreads();  // previous compute done before overwrite
#pragma unroll
    for (int pass = 0; pass < 4; ++pass) {  // 64 rows x 16 chunks of 4 fp32
      const int idx = pass * 256 + tid;
      const int row = idx >> 4, c4 = (idx & 15) * 4;
      const f32x4 v = *(const f32x4*)&xn[row * 64 + c4];
      *(f16x4*)&xs[(row + 4) * 72 + c4] = pack4(v);
    }
    __syncthreads();

    f32x16 acc;
#pragma unroll
    for (int i = 0; i < 16; ++i) acc[i] = 0.f;
#pragma unroll
    for (int ks = 0; ks < 12; ++ks) {
      const int k = ks >> 2;
      const int c0 = (ks & 3) * 16 + hi * 8;
      const f16x8 b = *(const f16x8*)&xs[(th * 32 + rl + 2 * k) * 72 + c0];
      acc = MFMA32(wh[ks], b, acc);
    }
    const int t = th * 32 + rl;
    f16* hrowt = h16t + ((size_t)t * NPTS + n) * 64;
#pragma unroll
    for (int q = 0; q < 4; ++q) {
      const f32x4 sub = {acc[4 * q], acc[4 * q + 1], acc[4 * q + 2], acc[4 * q + 3]};
      *(f16x4*)&hrowt[s * 32 + 8 * q + 4 * hi] = pack4_relu(sub, bias[q]);
    }
  }
}

// ---------------------------------------------------------------------------
// gather (r20: 2-deep row pipeline): agg16t[t][n][:] = masked-mean_s
// h16t[t][idx[t,n,s]][:] (fallback self). Octet per (t,n) pair; lane reads
// 16B -> one wave gather serves 8 pairs; idx/mask = one coalesced wave load,
// broadcast via __shfl. Pipeline: iteration j+1's 8 rows are ISSUED (using
// j+1's prefetched indices) before consuming iteration j's rows -> the
// consume VALU overlaps the next loads' L2 latency. Plain loads/stores only
// (r17: nontemporal broke integrity). Walk: 125 blocks/XCD x 4 waves x 8
// pairs = 4000 pairs/step, stride 4000, 20 steps = the XCD's full 80000;
// <=1-2 concurrent t-slabs/XCD; octet never straddles t (10000 % 8 == 0).
// agg t-major: one store = 8 consecutive n rows = 1KB contiguous.
// ---------------------------------------------------------------------------
__global__ __launch_bounds__(256) void gather_kernel(
    const f16* __restrict__ h16t, const int* __restrict__ nidx,
    const int* __restrict__ nmask, f16* __restrict__ agg16t) {
  const int tid = threadIdx.x;
  const int wv = tid >> 6, lane = tid & 63;
  const int oct = lane >> 3, sl8 = lane & 7;            // octet, sublane
  const int xcd = blockIdx.x & 7, q = blockIdx.x >> 3;  // q in [0,125)
  const uint4* h128 = (const uint4*)h16t;               // 16B units
  uint4* agg128 = (uint4*)agg16t;

  int t0 = xcd * 8;
  int n0 = (q * 4 + wv) * 8;  // octet base in [0,4000), 8-aligned
  int cm;                     // current masks (per-lane, octet-grouped)
  uint4 u[8];                 // current 8 rows for this octet's pair
  {
    const size_t pr = ((size_t)t0 * NPTS + n0) * SDIM;
    const int ci = nidx[pr + lane];
    cm = nmask[pr + lane];
    const uint32_t tb = (uint32_t)t0 * (NPTS * 8) + sl8;
#pragma unroll
    for (int s = 0; s < SDIM; ++s) {
      const int is = __shfl(ci, oct * 8 + s, 64);
      u[s] = h128[tb + (uint32_t)is * 8u];
    }
  }
  int t1 = t0, n1 = n0 + GSTRIDE;
  if (n1 >= NPTS) { n1 -= NPTS; ++t1; }
  int ci1, cm1;
  {
    const size_t pr = ((size_t)t1 * NPTS + n1) * SDIM;  // GJ >= 2
    ci1 = nidx[pr + lane];
    cm1 = nmask[pr + lane];
  }

  for (int j = 0; j < GJ; ++j) {
    // issue next iteration's rows before consuming the current ones
    uint4 un[8];
    if (j + 1 < GJ) {
      const uint32_t tbn = (uint32_t)t1 * (NPTS * 8) + sl8;
#pragma unroll
      for (int s = 0; s < SDIM; ++s) {
        const int is = __shfl(ci1, oct * 8 + s, 64);
        un[s] = h128[tbn + (uint32_t)is * 8u];
      }
    }
    // prefetch indices for iteration j+2
    int t2 = t1, n2 = n1 + GSTRIDE;
    if (n2 >= NPTS) { n2 -= NPTS; ++t2; }
    int ci2 = 0, cm2 = 0;
    if (j + 2 < GJ) {
      const size_t pr = ((size_t)t2 * NPTS + n2) * SDIM;
      ci2 = nidx[pr + lane];
      cm2 = nmask[pr + lane];
    }
    // consume current
    float a[8] = {0.f, 0.f, 0.f, 0.f, 0.f, 0.f, 0.f, 0.f};
    float cnt = 0.f;
#pragma unroll
    for (int s = 0; s < SDIM; ++s) {
      const float m = (__shfl(cm, oct * 8 + s, 64) != 0) ? 1.f : 0.f;
      const f16x2 p0 = __builtin_bit_cast(f16x2, u[s].x);
      const f16x2 p1 = __builtin_bit_cast(f16x2, u[s].y);
      const f16x2 p2 = __builtin_bit_cast(f16x2, u[s].z);
      const f16x2 p3 = __builtin_bit_cast(f16x2, u[s].w);
      a[0] = fmaf(m, (float)p0[0], a[0]);
      a[1] = fmaf(m, (float)p0[1], a[1]);
      a[2] = fmaf(m, (float)p1[0], a[2]);
      a[3] = fmaf(m, (float)p1[1], a[3]);
      a[4] = fmaf(m, (float)p2[0], a[4]);
      a[5] = fmaf(m, (float)p2[1], a[5]);
      a[6] = fmaf(m, (float)p3[0], a[6]);
      a[7] = fmaf(m, (float)p3[1], a[7]);
      cnt += m;
    }
    uint4 outv;
    if (cnt > 0.f) {
      const float inv = 1.f / cnt;
      const f16x4 lo4 = pack4((f32x4){a[0] * inv, a[1] * inv, a[2] * inv, a[3] * inv});
      const f16x4 hi4 = pack4((f32x4){a[4] * inv, a[5] * inv, a[6] * inv, a[7] * inv});
      const uint2 lo = __builtin_bit_cast(uint2, lo4);
      const uint2 hi = __builtin_bit_cast(uint2, hi4);
      outv.x = lo.x; outv.y = lo.y; outv.z = hi.x; outv.w = hi.y;
    } else {  // fallback: self row (exec-masked)
      const uint32_t tb = (uint32_t)t0 * (NPTS * 8) + sl8;
      outv = h128[tb + (uint32_t)(n0 + oct) * 8u];
    }
    agg128[((size_t)t0 * NPTS + (n0 + oct)) * 8 + sl8] = outv;
    // shift pipeline
#pragma unroll
    for (int s = 0; s < SDIM; ++s) u[s] = un[s];
    cm = cm1;
    t0 = t1; n0 = n1;
    t1 = t2; n1 = n2;
    ci1 = ci2; cm1 = cm2;
  }
}

// ---------------------------------------------------------------------------
// fused fc+conv2 (NG=4, r18 version): z never touches global (saves its
// 328MB round-trip). Per g: stage hs/as (both t-major: row (t,n) = one full
// 128B line) -> fc MFMA (wave w owns hc slice [32w,32w+32), both t-halves)
// writes relu(z) f16 into zs[68][136] LDS (rows 0-3 = causal pad) ->
// barrier -> conv2 MFMA (wave w: M-slice w>>1, t-half w&1) -> out fp32.
// VGPR ~108 -> 16 waves/CU cap (r19 lesson: occupancy is VGPR-bound here).
// ---------------------------------------------------------------------------
__global__ __launch_bounds__(256) void fc_conv2_kernel(
    const f16* __restrict__ h16t, const f16* __restrict__ agg16t,
    const f16* __restrict__ wfh, const float* __restrict__ bfc,
    const f16* __restrict__ w2h, const float* __restrict__ b2,
    float* __restrict__ out) {
  __shared__ f16 hs[64 * 72];
  __shared__ f16 as2[64 * 72];
  __shared__ f16 zs[68 * 136];
  const int tid = threadIdx.x;
  const int w = tid >> 6, lane = tid & 63;
  const int rl = lane & 31, hi = lane >> 5;
  f16x8 whf[8];
#pragma unroll
  for (int ks = 0; ks < 8; ++ks)
    whf[ks] = *(const f16x8*)&wfh[((w * 8 + ks) * 64 + lane) * 8];
  f32x4 biasf[4];
#pragma unroll
  for (int q = 0; q < 4; ++q)
    biasf[q] = *(const f32x4*)&bfc[w * 32 + 8 * q + 4 * hi];
  const int s2 = w >> 1, th2 = w & 1;
  f16x8 wh2[24];
#pragma unroll
  for (int ks = 0; ks < 24; ++ks)
    wh2[ks] = *(const f16x8*)&w2h[((s2 * 24 + ks) * 64 + lane) * 8];
  f32x4 bias2[4];
#pragma unroll
  for (int q = 0; q < 4; ++q)
    bias2[q] = *(const f32x4*)&b2[s2 * 32 + 8 * q + 4 * hi];
  // zs rows 0-3 (causal pad) = 544 f16 = 136 f16x4, within 256 threads.
  if (tid < 136) ((f16x4*)zs)[tid] = (f16x4){(f16)0, (f16)0, (f16)0, (f16)0};

  for (int g = 0; g < NG; ++g) {
    const int n = blockIdx.x * NG + g;
    if (g) __syncthreads();  // prev conv2 done with zs, prev fc done with hs/as
#pragma unroll
    for (int pass = 0; pass < 2; ++pass) {  // 64 rows x 8 chunks of 8 f16
      const int idx = pass * 256 + tid;
      const int row = idx >> 3, c8 = (idx & 7) * 8;
      *(f16x8*)&hs[row * 72 + c8] =
          *(const f16x8*)&h16t[((size_t)row * NPTS + n) * 64 + c8];
      *(f16x8*)&as2[row * 72 + c8] =
          *(const f16x8*)&agg16t[((size_t)row * NPTS + n) * 64 + c8];
    }
    __syncthreads();

    // fc phase: z[t][32w..32w+32) for all 64 t
#pragma unroll
    for (int tf = 0; tf < 2; ++tf) {
      f32x16 accf;
#pragma unroll
      for (int i = 0; i < 16; ++i) accf[i] = 0.f;
      const int t = tf * 32 + rl;
#pragma unroll
      for (int ks = 0; ks < 8; ++ks) {
        const int c0 = (ks & 3) * 16 + hi * 8;
        const f16x8 b = (ks < 4) ? *(const f16x8*)&hs[t * 72 + c0]
                                 : *(const f16x8*)&as2[t * 72 + c0];
        accf = MFMA32(whf[ks], b, accf);
      }
#pragma unroll
      for (int q = 0; q < 4; ++q) {
        const f32x4 sub = {accf[4 * q], accf[4 * q + 1], accf[4 * q + 2], accf[4 * q + 3]};
        *(f16x4*)&zs[(t + 4) * 136 + w * 32 + 8 * q + 4 * hi] =
            pack4_relu(sub, biasf[q]);
      }
    }
    __syncthreads();

    // conv2 phase
    f32x16 acc;
#pragma unroll
    for (int i = 0; i < 16; ++i) acc[i] = 0.f;
#pragma unroll
    for (int ks = 0; ks < 24; ++ks) {
      const int k = ks >> 3;
      const int c0 = (ks & 7) * 16 + hi * 8;
      const f16x8 b = *(const f16x8*)&zs[(th2 * 32 + rl + 2 * k) * 136 + c0];
      acc = MFMA32(wh2[ks], b, acc);
    }
    const int t = th2 * 32 + rl;
    float* orow = out + ((size_t)n * 64 + t) * 64;
#pragma unroll
    for (int q = 0; q < 4; ++q) {
      f32x4 v;
      v[0] = fmaxf(acc[4 * q + 0] + bias2[q][0], 0.f);
      v[1] = fmaxf(acc[4 * q + 1] + bias2[q][1], 0.f);
      v[2] = fmaxf(acc[4 * q + 2] + bias2[q][2], 0.f);
      v[3] = fmaxf(acc[4 * q + 3] + bias2[q][3], 0.f);
      *(f32x4*)&orow[s2 * 32 + 8 * q + 4 * hi] = v;
    }
  }
}

// ---------------------------------------------------------------------------
// Workspace (f16 units): w1h 12288 | wfh 16384 | w2h 24576 |
//   h16t 41M (t-major) | agg16t 41M (t-major)   ~164 MB.
// ---------------------------------------------------------------------------
extern "C" void kernel_launch(void* const* d_in, const int* in_sizes, int n_in,
                              void* d_out, int out_size, void* d_ws, size_t ws_size,
                              hipStream_t stream) {
  (void)in_sizes; (void)n_in; (void)out_size; (void)ws_size;
  const float* x   = (const float*)d_in[0];
  const float* W1  = (const float*)d_in[1];
  const float* b1  = (const float*)d_in[2];
  const float* Wfc = (const float*)d_in[3];
  const float* bfc = (const float*)d_in[4];
  const float* W2  = (const float*)d_in[5];
  const float* b2  = (const float*)d_in[6];
  const int* nidx  = (const int*)d_in[7];
  const int* nmask = (const int*)d_in[8];
  float* out = (float*)d_out;

  f16* wsf = (f16*)d_ws;
  f16* w1h = wsf;
  f16* wfh = w1h + 12288;
  f16* w2h = wfh + 16384;
  f16* h16t = w2h + 24576;
  f16* agg16t = h16t + (size_t)NPTS * TDIM * FDIM;

  prep_kernel<<<96, 256, 0, stream>>>(W1, Wfc, W2, w1h, wfh, w2h);
  conv1_kernel<<<NPTS / CNG, 256, 0, stream>>>(x, w1h, b1, h16t);
  gather_kernel<<<GNB, 256, 0, stream>>>(h16t, nidx, nmask, agg16t);
  fc_conv2_kernel<<<NPTS / NG, 256, 0, stream>>>(h16t, agg16t, wfh, bfc,
                                                 w2h, b2, out);
}

// Round 21
// 213.418 us; speedup vs baseline: 1.0624x; 1.0171x over previous
//
#include <hip/hip_runtime.h>
#include <cstddef>
#include <cstdint>

#define NPTS 10000
#define TDIM 64
#define CINDIM 64
#define FDIM 64
#define HIDDIM 128
#define SDIM 8
#define NG 4     // n's per block in matmul kernels
#define GNB 2000 // gather blocks (250 per XCD)

typedef _Float16 f16;
typedef _Float16 f16x2 __attribute__((ext_vector_type(2)));
typedef _Float16 f16x4 __attribute__((ext_vector_type(4)));
typedef _Float16 f16x8 __attribute__((ext_vector_type(8)));
typedef float f32x4 __attribute__((ext_vector_type(4)));
typedef float f32x16 __attribute__((ext_vector_type(16)));

#define MFMA32(a, b, c) __builtin_amdgcn_mfma_f32_32x32x16_f16((a), (b), (c), 0, 0, 0)

static __device__ __forceinline__ f16x2 pk(float a, float b) {
  return __builtin_bit_cast(f16x2, __builtin_amdgcn_cvt_pkrtz(a, b));
}
static __device__ __forceinline__ f16x4 pack4(f32x4 p) {
  f16x2 h0 = pk(p[0], p[1]), h1 = pk(p[2], p[3]);
  return __builtin_shufflevector(h0, h1, 0, 1, 2, 3);
}
static __device__ __forceinline__ f16x4 pack4_relu(f32x4 v, f32x4 bias) {
  f16x4 r;
  r[0] = (f16)fmaxf(v[0] + bias[0], 0.f);
  r[1] = (f16)fmaxf(v[1] + bias[1], 0.f);
  r[2] = (f16)fmaxf(v[2] + bias[2], 0.f);
  r[3] = (f16)fmaxf(v[3] + bias[3], 0.f);
  return r;
}

// ---------------------------------------------------------------------------
// prep: round weights to f16 and pre-shuffle into 32x32x16 A-frag order:
// lane l holds A[row=l&31][kk=(l>>5)*8+j]. Storage [slice][ks][lane][j],
// kk = ks*16+(l>>5)*8+j.
//   conv1 kk = k*64 + c   (K=192, 12 ks, 2 slices)
//   fc    kk = c          (K=128,  8 ks, 4 slices)
//   conv2 kk = k*128 + c  (K=384, 24 ks, 2 slices)
// ---------------------------------------------------------------------------
__global__ __launch_bounds__(256) void prep_kernel(
    const float* __restrict__ W1, const float* __restrict__ Wfc,
    const float* __restrict__ W2, f16* __restrict__ w1h,
    f16* __restrict__ wfh, f16* __restrict__ w2h) {
  const int idx = blockIdx.x * 256 + threadIdx.x;
  const int j = idx & 7;
  if (idx < 2 * 12 * 512) {  // w1
    const int s = idx / 6144, rem = idx % 6144;
    const int ks = rem / 512, l = (rem % 512) >> 3;
    const int kk = ks * 16 + ((l >> 5) << 3) + j;
    const int k = kk >> 6, c = kk & 63, f = s * 32 + (l & 31);
    w1h[idx] = (f16)W1[f * 192 + c * 3 + k];
  }
  if (idx < 4 * 8 * 512) {  // wfc
    const int s = idx / 4096, rem = idx % 4096;
    const int ks = rem / 512, l = (rem % 512) >> 3;
    const int kk = ks * 16 + ((l >> 5) << 3) + j;
    const int hc = s * 32 + (l & 31);
    wfh[idx] = (f16)Wfc[hc * 128 + kk];
  }
  if (idx < 2 * 24 * 512) {  // w2
    const int s = idx / 12288, rem = idx % 12288;
    const int ks = rem / 512, l = (rem % 512) >> 3;
    const int kk = ks * 16 + ((l >> 5) << 3) + j;
    const int k = kk >> 7, c = kk & 127, f = s * 32 + (l & 31);
    w2h[idx] = (f16)W2[f * 384 + c * 3 + k];
  }
}

// ---------------------------------------------------------------------------
// conv1: relu(b1 + sum_{k,c} W1[f,c,k] x[n, t-4+2k, c]).
// LDS-staged: x[n] tile (64x64 fp32) loaded coalesced, packed to f16 into
// xs[68][72] (rows 0-3 = causal zero pad). Wave w: M-slice s=w>>1, t-half
// th=w&1. Writes h t-major only (h16t).
// ---------------------------------------------------------------------------
__global__ __launch_bounds__(256) void conv1_kernel(
    const float* __restrict__ x, const f16* __restrict__ w1h,
    const float* __restrict__ b1, f16* __restrict__ h16t) {
  __shared__ f16 xs[68 * 72];
  const int tid = threadIdx.x;
  const int w = tid >> 6, lane = tid & 63;
  const int s = w >> 1, th = w & 1;
  const int rl = lane & 31, hi = lane >> 5;
  f16x8 wh[12];
#pragma unroll
  for (int ks = 0; ks < 12; ++ks)
    wh[ks] = *(const f16x8*)&w1h[((s * 12 + ks) * 64 + lane) * 8];
  f32x4 bias[4];
#pragma unroll
  for (int q = 0; q < 4; ++q) bias[q] = *(const f32x4*)&b1[s * 32 + 8 * q + 4 * hi];
  // rows 0-3 (causal pad) = 288 f16 = 144 f16x2; 144 <= 256 threads -> full.
  if (tid < 144) ((f16x2*)xs)[tid] = (f16x2){(f16)0, (f16)0};

  for (int g = 0; g < NG; ++g) {
    const int n = blockIdx.x * NG + g;
    const float* xn = x + (size_t)n * (TDIM * CINDIM);
    if (g) __syncthreads();  // previous compute done before overwrite
#pragma unroll
    for (int pass = 0; pass < 4; ++pass) {  // 64 rows x 16 chunks of 4 fp32
      const int idx = pass * 256 + tid;
      const int row = idx >> 4, c4 = (idx & 15) * 4;
      const f32x4 v = *(const f32x4*)&xn[row * 64 + c4];
      *(f16x4*)&xs[(row + 4) * 72 + c4] = pack4(v);
    }
    __syncthreads();

    f32x16 acc;
#pragma unroll
    for (int i = 0; i < 16; ++i) acc[i] = 0.f;
#pragma unroll
    for (int ks = 0; ks < 12; ++ks) {
      const int k = ks >> 2;
      const int c0 = (ks & 3) * 16 + hi * 8;
      const f16x8 b = *(const f16x8*)&xs[(th * 32 + rl + 2 * k) * 72 + c0];
      acc = MFMA32(wh[ks], b, acc);
    }
    const int t = th * 32 + rl;
    f16* hrowt = h16t + ((size_t)t * NPTS + n) * 64;
#pragma unroll
    for (int q = 0; q < 4; ++q) {
      const f32x4 sub = {acc[4 * q], acc[4 * q + 1], acc[4 * q + 2], acc[4 * q + 3]};
      *(f16x4*)&hrowt[s * 32 + 8 * q + 4 * hi] = pack4_relu(sub, bias[q]);
    }
  }
}

// ---------------------------------------------------------------------------
// gather: agg[n][t][:] = masked-mean_s h16t[t][idx[t,n,s]][:] (fallback self).
// Octet per (t,n) pair: lane = oct*8+sl8; each octet owns one pair, lane
// reads 16B (dwordx4) -> one wave gather instruction serves 8 pairs. idx/mask
// for the octet-group = 64 elements = ONE coalesced wave load each
// (nidx[(t*NPTS+n)*8 + lane]), broadcast via __shfl(v, oct*8+s). Walk: 250
// blocks/XCD, stride 8000, 10 iters; <=2 concurrent t-slabs/XCD (2.6MB <
// 4MB L2); octet never straddles t (10000 % 8 == 0).
// ---------------------------------------------------------------------------
__global__ __launch_bounds__(256) void gather_kernel(
    const f16* __restrict__ h16t, const int* __restrict__ nidx,
    const int* __restrict__ nmask, f16* __restrict__ agg16) {
  const int tid = threadIdx.x;
  const int wv = tid >> 6, lane = tid & 63;
  const int oct = lane >> 3, sl8 = lane & 7;            // octet, sublane
  const int xcd = blockIdx.x & 7, q = blockIdx.x >> 3;  // q in [0,250)
  const uint4* h128 = (const uint4*)h16t;               // 16B units
  uint4* agg128 = (uint4*)agg16;

  int t = xcd * 8;
  int n = (q * 4 + wv) * 8;  // octet base in [0,8000), 8-aligned
  int ci, cm;
  {
    const size_t pr = ((size_t)t * NPTS + n) * SDIM;
    ci = nidx[pr + lane];
    cm = nmask[pr + lane];
  }
  for (int j = 0; j < 10; ++j) {
    int tn = t, nn = n + 8000;
    if (nn >= NPTS) { nn -= NPTS; ++tn; }  // stride < NPTS: at most one wrap
    int pi = 0, pm = 0;
    if (j + 1 < 10) {  // prefetch next octet-group's idx/mask
      const size_t pr = ((size_t)tn * NPTS + nn) * SDIM;
      pi = nidx[pr + lane];
      pm = nmask[pr + lane];
    }
    const uint32_t tb = (uint32_t)t * (NPTS * 8) + sl8;  // uint4 units
    uint4 u[8];
#pragma unroll
    for (int s = 0; s < SDIM; ++s) {
      const int is = __shfl(ci, oct * 8 + s, 64);
      u[s] = h128[tb + (uint32_t)is * 8u];
    }
    float a[8] = {0.f, 0.f, 0.f, 0.f, 0.f, 0.f, 0.f, 0.f};
    float cnt = 0.f;
#pragma unroll
    for (int s = 0; s < SDIM; ++s) {
      const float m = (__shfl(cm, oct * 8 + s, 64) != 0) ? 1.f : 0.f;
      const f16x2 p0 = __builtin_bit_cast(f16x2, u[s].x);
      const f16x2 p1 = __builtin_bit_cast(f16x2, u[s].y);
      const f16x2 p2 = __builtin_bit_cast(f16x2, u[s].z);
      const f16x2 p3 = __builtin_bit_cast(f16x2, u[s].w);
      a[0] = fmaf(m, (float)p0[0], a[0]);
      a[1] = fmaf(m, (float)p0[1], a[1]);
      a[2] = fmaf(m, (float)p1[0], a[2]);
      a[3] = fmaf(m, (float)p1[1], a[3]);
      a[4] = fmaf(m, (float)p2[0], a[4]);
      a[5] = fmaf(m, (float)p2[1], a[5]);
      a[6] = fmaf(m, (float)p3[0], a[6]);
      a[7] = fmaf(m, (float)p3[1], a[7]);
      cnt += m;
    }
    uint4 outv;
    if (cnt > 0.f) {
      const float inv = 1.f / cnt;
      const f16x4 lo4 = pack4((f32x4){a[0] * inv, a[1] * inv, a[2] * inv, a[3] * inv});
      const f16x4 hi4 = pack4((f32x4){a[4] * inv, a[5] * inv, a[6] * inv, a[7] * inv});
      const uint2 lo = __builtin_bit_cast(uint2, lo4);
      const uint2 hi = __builtin_bit_cast(uint2, hi4);
      outv.x = lo.x; outv.y = lo.y; outv.z = hi.x; outv.w = hi.y;
    } else {  // fallback: self row (exec-masked)
      outv = h128[tb + (uint32_t)(n + oct) * 8u];
    }
    agg128[((size_t)(n + oct) * 64 + t) * 8 + sl8] = outv;
    ci = pi; cm = pm; t = tn; n = nn;
  }
}

// ---------------------------------------------------------------------------
// fused fc+conv2: z never touches global (saves its 328MB round-trip).
// Per g: stage hs/as -> fc MFMA (wave w owns hc slice [32w,32w+32), both
// t-halves) writes relu(z) f16 into zs[68][136] LDS (rows 0-3 = causal pad)
// -> barrier -> conv2 MFMA (wave w: M-slice w>>1, t-half w&1) -> out fp32.
// Numerics identical to the split version (z rounds to f16 either way).
// ---------------------------------------------------------------------------
__global__ __launch_bounds__(256) void fc_conv2_kernel(
    const f16* __restrict__ h16t, const f16* __restrict__ agg16,
    const f16* __restrict__ wfh, const float* __restrict__ bfc,
    const f16* __restrict__ w2h, const float* __restrict__ b2,
    float* __restrict__ out) {
  __shared__ f16 hs[64 * 72];
  __shared__ f16 as2[64 * 72];
  __shared__ f16 zs[68 * 136];
  const int tid = threadIdx.x;
  const int w = tid >> 6, lane = tid & 63;
  const int rl = lane & 31, hi = lane >> 5;
  f16x8 whf[8];
#pragma unroll
  for (int ks = 0; ks < 8; ++ks)
    whf[ks] = *(const f16x8*)&wfh[((w * 8 + ks) * 64 + lane) * 8];
  f32x4 biasf[4];
#pragma unroll
  for (int q = 0; q < 4; ++q)
    biasf[q] = *(const f32x4*)&bfc[w * 32 + 8 * q + 4 * hi];
  const int s2 = w >> 1, th2 = w & 1;
  f16x8 wh2[24];
#pragma unroll
  for (int ks = 0; ks < 24; ++ks)
    wh2[ks] = *(const f16x8*)&w2h[((s2 * 24 + ks) * 64 + lane) * 8];
  f32x4 bias2[4];
#pragma unroll
  for (int q = 0; q < 4; ++q)
    bias2[q] = *(const f32x4*)&b2[s2 * 32 + 8 * q + 4 * hi];
  // zs rows 0-3 (causal pad) = 544 f16 = 136 f16x4, within 256 threads.
  if (tid < 136) ((f16x4*)zs)[tid] = (f16x4){(f16)0, (f16)0, (f16)0, (f16)0};

  for (int g = 0; g < NG; ++g) {
    const int n = blockIdx.x * NG + g;
    if (g) __syncthreads();  // prev conv2 done with zs, prev fc done with hs/as
#pragma unroll
    for (int pass = 0; pass < 2; ++pass) {  // 64 rows x 8 chunks of 8 f16
      const int idx = pass * 256 + tid;
      const int row = idx >> 3, c8 = (idx & 7) * 8;
      *(f16x8*)&hs[row * 72 + c8] =
          *(const f16x8*)&h16t[((size_t)row * NPTS + n) * 64 + c8];
      *(f16x8*)&as2[row * 72 + c8] =
          *(const f16x8*)&agg16[((size_t)n * 64 + row) * 64 + c8];
    }
    __syncthreads();

    // fc phase: z[t][32w..32w+32) for all 64 t
#pragma unroll
    for (int tf = 0; tf < 2; ++tf) {
      f32x16 accf;
#pragma unroll
      for (int i = 0; i < 16; ++i) accf[i] = 0.f;
      const int t = tf * 32 + rl;
#pragma unroll
      for (int ks = 0; ks < 8; ++ks) {
        const int c0 = (ks & 3) * 16 + hi * 8;
        const f16x8 b = (ks < 4) ? *(const f16x8*)&hs[t * 72 + c0]
                                 : *(const f16x8*)&as2[t * 72 + c0];
        accf = MFMA32(whf[ks], b, accf);
      }
#pragma unroll
      for (int q = 0; q < 4; ++q) {
        const f32x4 sub = {accf[4 * q], accf[4 * q + 1], accf[4 * q + 2], accf[4 * q + 3]};
        *(f16x4*)&zs[(t + 4) * 136 + w * 32 + 8 * q + 4 * hi] =
            pack4_relu(sub, biasf[q]);
      }
    }
    __syncthreads();

    // conv2 phase
    f32x16 acc;
#pragma unroll
    for (int i = 0; i < 16; ++i) acc[i] = 0.f;
#pragma unroll
    for (int ks = 0; ks < 24; ++ks) {
      const int k = ks >> 3;
      const int c0 = (ks & 7) * 16 + hi * 8;
      const f16x8 b = *(const f16x8*)&zs[(th2 * 32 + rl + 2 * k) * 136 + c0];
      acc = MFMA32(wh2[ks], b, acc);
    }
    const int t = th2 * 32 + rl;
    float* orow = out + ((size_t)n * 64 + t) * 64;
#pragma unroll
    for (int q = 0; q < 4; ++q) {
      f32x4 v;
      v[0] = fmaxf(acc[4 * q + 0] + bias2[q][0], 0.f);
      v[1] = fmaxf(acc[4 * q + 1] + bias2[q][1], 0.f);
      v[2] = fmaxf(acc[4 * q + 2] + bias2[q][2], 0.f);
      v[3] = fmaxf(acc[4 * q + 3] + bias2[q][3], 0.f);
      *(f32x4*)&orow[s2 * 32 + 8 * q + 4 * hi] = v;
    }
  }
}

// ---------------------------------------------------------------------------
// Workspace (f16 units): w1h 12288 | wfh 16384 | w2h 24576 |
//   h16t 41M (t-major) | agg16 41M (n-major)   ~164 MB.
// ---------------------------------------------------------------------------
extern "C" void kernel_launch(void* const* d_in, const int* in_sizes, int n_in,
                              void* d_out, int out_size, void* d_ws, size_t ws_size,
                              hipStream_t stream) {
  (void)in_sizes; (void)n_in; (void)out_size; (void)ws_size;
  const float* x   = (const float*)d_in[0];
  const float* W1  = (const float*)d_in[1];
  const float* b1  = (const float*)d_in[2];
  const float* Wfc = (const float*)d_in[3];
  const float* bfc = (const float*)d_in[4];
  const float* W2  = (const float*)d_in[5];
  const float* b2  = (const float*)d_in[6];
  const int* nidx  = (const int*)d_in[7];
  const int* nmask = (const int*)d_in[8];
  float* out = (float*)d_out;

  f16* wsf = (f16*)d_ws;
  f16* w1h = wsf;
  f16* wfh = w1h + 12288;
  f16* w2h = wfh + 16384;
  f16* h16t = w2h + 24576;
  f16* agg16 = h16t + (size_t)NPTS * TDIM * FDIM;

  prep_kernel<<<96, 256, 0, stream>>>(W1, Wfc, W2, w1h, wfh, w2h);
  conv1_kernel<<<NPTS / NG, 256, 0, stream>>>(x, w1h, b1, h16t);
  gather_kernel<<<GNB, 256, 0, stream>>>(h16t, nidx, nmask, agg16);
  fc_conv2_kernel<<<NPTS / NG, 256, 0, stream>>>(h16t, agg16, wfh, bfc,
                                                 w2h, b2, out);
}